// Round 3
// baseline (378.311 us; speedup 1.0000x reference)
//
#include <hip/hip_runtime.h>
#include <hip/hip_bf16.h>
#include <math.h>

// Problem constants (from reference)
#define B_SZ   128
#define HDIM   256
#define NG     1280     // 5*H
#define NNODES 1023
#define VOCAB  2048

typedef unsigned int uint32;
typedef short  short8v  __attribute__((ext_vector_type(8)));   // 8 x bf16 (4 VGPR)
typedef float  float4v  __attribute__((ext_vector_type(4)));   // MFMA C/D frag

__device__ __forceinline__ float sigm(float x) {
    return 1.0f / (1.0f + __expf(-x));
}
__device__ __forceinline__ float tanh_fast(float x) {
    return 2.0f / (1.0f + __expf(-2.0f * x)) - 1.0f;
}
__device__ __forceinline__ float bf2f(unsigned short u) {
    return __uint_as_float(((uint32)u) << 16);
}
__device__ __forceinline__ unsigned short f2bf(float f) {
    uint32 x = __float_as_uint(f);
    uint32 r = (x + 0x7FFFu + ((x >> 16) & 1u)) >> 16;   // RNE
    return (unsigned short)r;
}

// Async 16B/lane global->LDS DMA. LDS dest = wave-uniform base + lane*16.
__device__ __forceinline__ void dma16(const unsigned short* gptr, unsigned short* lptr) {
    __builtin_amdgcn_global_load_lds(
        (const __attribute__((address_space(1))) void*)gptr,
        (__attribute__((address_space(3))) void*)lptr, 16, 0, 0);
}

// ---------------------------------------------------------------------------
// embb = bf16(emb) : 2048 x 256.  A-operand for the EW builder + levels' x.
// ---------------------------------------------------------------------------
__global__ __launch_bounds__(256) void embb_kernel(
    const float* __restrict__ emb, unsigned short* __restrict__ embb)
{
    const int t = blockIdx.x * 256 + threadIdx.x;
    const float4 v0 = *(const float4*)(emb + (size_t)t * 8);
    const float4 v1 = *(const float4*)(emb + (size_t)t * 8 + 4);
    short8v o;
    o[0] = (short)f2bf(v0.x); o[1] = (short)f2bf(v0.y);
    o[2] = (short)f2bf(v0.z); o[3] = (short)f2bf(v0.w);
    o[4] = (short)f2bf(v1.x); o[5] = (short)f2bf(v1.y);
    o[6] = (short)f2bf(v1.z); o[7] = (short)f2bf(v1.w);
    *(short8v*)(embb + (size_t)t * 8) = o;
}

// ---------------------------------------------------------------------------
// WTf: fragment-ready bf16 repack of [Ul;Ur;Wx] (K=768, N=1280) for MFMA B.
// short8 index = (ng*24 + ks)*64 + lane ; lane = q*16 + c
//   holds B[k = ks*32 + q*8 + j][col = ng*16 + c],  j = 0..7
// Levels now use ALL 24 ks slots (K=768: [hl|hr|x] @ [Ul;Ur;Wx]);
// the EW builder uses ks 16..23 (Wx) only.
// ---------------------------------------------------------------------------
__global__ __launch_bounds__(256) void prep_wtf(
    const float* __restrict__ Ul, const float* __restrict__ Ur,
    const float* __restrict__ Wx, unsigned short* __restrict__ WTf)
{
    const int t = blockIdx.x * 256 + threadIdx.x;   // 0..122879
    const int l = t & 63;
    const int q = l >> 4, c = l & 15;
    const int ks = (t >> 6) % 24;
    const int ng = t / (24 * 64);                    // 0..79
    const int col = ng * 16 + c;
    const int k = ks * 32 + q * 8;
    const float* src = (k < 256) ? (Ul + (size_t)k * NG + col)
                     : (k < 512) ? (Ur + (size_t)(k - 256) * NG + col)
                                 : (Wx + (size_t)(k - 512) * NG + col);
    short8v v;
    #pragma unroll
    for (int j = 0; j < 8; ++j) v[j] = (short)f2bf(src[(size_t)j * NG]);
    *(short8v*)(WTf + (size_t)t * 8) = v;
}

// ---------------------------------------------------------------------------
// EWb = bf16(embb @ Wx + b) via MFMA.  Only consumed by leaftab now.
// ---------------------------------------------------------------------------
__global__ __launch_bounds__(256, 2) void ewb_mfma(
    const unsigned short* __restrict__ WTf, const unsigned short* __restrict__ embb,
    const float* __restrict__ bias, unsigned short* __restrict__ EWb)
{
    __shared__ __align__(16) unsigned short Ab[2][4096];   // 16 KB A dbuf
    __shared__ __align__(16) unsigned short wbE[20480];    // 40 KB: 5 gates x 64 rows x 64 cols

    const int tid  = threadIdx.x;
    const int lane = tid & 63;
    const int w    = tid >> 6;                  // 0..3 = col-tile
    const int quad = lane >> 4, col15 = lane & 15;
    const int jt = blockIdx.x;
    const int rowBase = blockIdx.y * 64;        // emb row
    const int jbase   = jt * 64;

    const unsigned short* agp[2];
    unsigned short* ldst[2];
    #pragma unroll
    for (int t = 0; t < 2; ++t) {
        const int ch = 2 * w + t, sub = ch >> 2, rt = ch & 3;
        const int srow = rowBase + rt * 16 + col15;
        agp[t]  = embb + (size_t)srow * HDIM + sub * 32 + quad * 8;
        ldst[t] = &Ab[0][0] + ch * 512;
    }

    const short8v* WTfv = (const short8v*)WTf;
    uint32 boff[5];
    #pragma unroll
    for (int g = 0; g < 5; ++g)
        boff[g] = ((g * 16 + jt * 4 + w) * 24 + 16) * 64 + lane;   // Wx section

    float4v acc[4][5];
    #pragma unroll
    for (int rt = 0; rt < 4; ++rt)
        #pragma unroll
        for (int g = 0; g < 5; ++g)
            #pragma unroll
            for (int e = 0; e < 4; ++e) acc[rt][g][e] = 0.0f;

    dma16(agp[0], ldst[0]); dma16(agp[1], ldst[1]);
    __syncthreads();

    #pragma unroll
    for (int s = 0; s < 4; ++s) {
        if (s < 3) {
            dma16(agp[0] + (s + 1) * 64, ldst[0] + ((s + 1) & 1) * 4096);
            dma16(agp[1] + (s + 1) * 64, ldst[1] + ((s + 1) & 1) * 4096);
        }
        #pragma unroll
        for (int sub = 0; sub < 2; ++sub) {
            short8v bf[5];
            #pragma unroll
            for (int g = 0; g < 5; ++g) bf[g] = WTfv[boff[g] + (s * 2 + sub) * 64];
            #pragma unroll
            for (int rt = 0; rt < 4; ++rt) {
                const short8v af = *(const short8v*)&Ab[s & 1][(sub * 4 + rt) * 512 + lane * 8];
                #pragma unroll
                for (int g = 0; g < 5; ++g)
                    acc[rt][g] = __builtin_amdgcn_mfma_f32_16x16x32_bf16(
                        af, bf[g], acc[rt][g], 0, 0, 0);
            }
        }
        __syncthreads();
    }

    const int jl = w * 16 + col15;
    const int j  = jbase + jl;
    float bz[5];
    #pragma unroll
    for (int g = 0; g < 5; ++g) bz[g] = bias[g * 256 + j];
    const int jchunk = jl >> 3, jpos = jl & 7;

    #pragma unroll
    for (int rt = 0; rt < 4; ++rt) {
        #pragma unroll
        for (int reg = 0; reg < 4; ++reg) {
            const int rr = rt * 16 + quad * 4 + reg;
            const int roff = ((jchunk + 2 * quad) & 7) * 8 + jpos;  // (rr>>2)&3==quad
            #pragma unroll
            for (int g = 0; g < 5; ++g)
                wbE[(g * 64 + rr) * 64 + roff] = f2bf(acc[rt][g][reg] + bz[g]);
        }
    }
    __syncthreads();

    #pragma unroll
    for (int k2 = 0; k2 < 10; ++k2) {
        const int c = tid + k2 * 256;                // 0..2559
        const int g = c >> 9, rr = (c >> 3) & 63, u = c & 7;
        const int ru = (u + 2 * ((rr >> 2) & 3)) & 7;
        const short8v v = *(const short8v*)&wbE[(g * 64 + rr) * 64 + ru * 8];
        *(short8v*)(EWb + (size_t)(rowBase + rr) * NG + g * 256 + jbase + u * 8) = v;
    }
}

// ---------------------------------------------------------------------------
// Leaf-as-table: leaf h/c depend ONLY on the token.
// Hleaf/Cleaf[2048][256] (2 MB, L2-resident) replace the entire 65k-row leaf
// GEMM + its 67 MB of h/c writes; d=8 gathers children from these tables.
// ---------------------------------------------------------------------------
__global__ __launch_bounds__(256) void leaftab_kernel(
    const unsigned short* __restrict__ EWb,
    unsigned short* __restrict__ Hleaf, unsigned short* __restrict__ Cleaf)
{
    const int t = blockIdx.x * 256 + threadIdx.x;   // 0..524287
    const int tok = t >> 8, j = t & 255;
    const float gi = bf2f(EWb[(size_t)tok * NG + j]);
    const float go = bf2f(EWb[(size_t)tok * NG + 768 + j]);
    const float gu = bf2f(EWb[(size_t)tok * NG + 1024 + j]);
    const float c = sigm(gi) * tanh_fast(gu);
    const float h = sigm(go) * tanh_fast(c);
    Hleaf[t] = f2bf(h);
    Cleaf[t] = f2bf(c);
}

// ---------------------------------------------------------------------------
// Inner level d (8..0): MFMA GEMM [hl|hr|x](Mx768) @ [Ul;Ur;Wx](768x1280)
// + bias + LSTM cell.
// R18 change: fold x@Wx INTO the GEMM (K 512->768, 12 dbuf steps).  The x
// rows are embb[tok_node], token-gathered by dma16's per-lane global source.
// This removes the 80-load/thread EW epilogue gather (dominant latency at
// every level, and EWb at 5.2 MB thrashed the 4 MiB per-XCD L2) at the cost
// of +50% MFMA on a kernel that was only 20% MfmaUtil.  Epilogue is now just
// bias (hoisted, 5 uniform loads) + child-c gather (32 u16) + cell math.
// ---------------------------------------------------------------------------
__global__ __launch_bounds__(256, 2) void level_kernel(
    const unsigned short* __restrict__ WTf, const int* __restrict__ tokens,
    const unsigned short* __restrict__ embb,
    const unsigned short* __restrict__ Hleaf, const unsigned short* __restrict__ Cleaf,
    const unsigned short* __restrict__ hsrc, const unsigned short* __restrict__ csrc,
    const float* __restrict__ bias,
    unsigned short* __restrict__ hdst, unsigned short* __restrict__ cdst,
    float* __restrict__ out, const int d)
{
    const int n = 1 << d;

    __shared__ __align__(16) unsigned short Ab[2][4096];     // 16 KB A dbuf (only LDS)

    const int tid  = threadIdx.x;
    const int lane = tid & 63;
    const int w    = tid >> 6;                  // 0..3 = col-tile
    const int quad = lane >> 4, col15 = lane & 15;
    const int jt = blockIdx.x;                  // 0..3 (fastest)
    const int rowBase = blockIdx.y * 64;
    const int jbase   = jt * 64;

    // ---- A staging: 8 chunks/step (ch = sub*4 + rt); wave w: ch = 2w, 2w+1.
    // k<256: left child h | 256..511: right child h | 512..767: x = embb[tok].
    // d<8: children are rows 2r,2r+1 of hsrc; d==8: token-indexed Hleaf rows.
    const unsigned short* agp_lo[2];
    const unsigned short* agp_hi[2];
    const unsigned short* agp_x[2];
    unsigned short* ldst[2];
    #pragma unroll
    for (int t = 0; t < 2; ++t) {
        const int ch = 2 * w + t, sub = ch >> 2, rt = ch & 3;
        const int srow = rowBase + rt * 16 + col15;
        const int b = srow >> d, i = srow & (n - 1);
        const int tokN = tokens[b * NNODES + (n - 1) + i];
        agp_x[t] = embb + (size_t)tokN * HDIM + sub * 32 + quad * 8;
        if (d == 8) {
            const int tokL = tokens[b * NNODES + 511 + 2 * i];
            const int tokR = tokens[b * NNODES + 512 + 2 * i];
            agp_lo[t] = Hleaf + (size_t)tokL * HDIM + sub * 32 + quad * 8;
            agp_hi[t] = Hleaf + (size_t)tokR * HDIM + sub * 32 + quad * 8;
        } else {
            agp_lo[t] = hsrc + (size_t)(2 * srow) * HDIM + sub * 32 + quad * 8;
            agp_hi[t] = agp_lo[t] + HDIM;
        }
        ldst[t] = &Ab[0][0] + ch * 512;
    }

    const short8v* WTfv = (const short8v*)WTf;
    uint32 boff[5];
    #pragma unroll
    for (int g = 0; g < 5; ++g)
        boff[g] = ((g * 16 + jt * 4 + w) * 24) * 64 + lane;   // full K=768 (24 ks)

    // Hoisted bias (uniform per column; L2-hot after first block).
    const int jl = w * 16 + col15;
    const int j  = jbase + jl;
    float bz[5];
    #pragma unroll
    for (int g = 0; g < 5; ++g) bz[g] = bias[g * 256 + j];

    float4v acc[4][5];
    #pragma unroll
    for (int rt = 0; rt < 4; ++rt)
        #pragma unroll
        for (int g = 0; g < 5; ++g)
            #pragma unroll
            for (int e = 0; e < 4; ++e) acc[rt][g][e] = 0.0f;

    dma16(agp_lo[0], ldst[0]); dma16(agp_lo[1], ldst[1]);   // step 0 (k<256)
    __syncthreads();

    #pragma unroll
    for (int s = 0; s < 12; ++s) {
        if (s < 11) {
            const int sn = s + 1;
            #pragma unroll
            for (int t = 0; t < 2; ++t) {
                const unsigned short* p = (sn < 4) ? (agp_lo[t] + sn * 64)
                                        : (sn < 8) ? (agp_hi[t] + (sn - 4) * 64)
                                                   : (agp_x[t]  + (sn - 8) * 64);
                dma16(p, ldst[t] + (sn & 1) * 4096);
            }
        }

        #pragma unroll
        for (int sub = 0; sub < 2; ++sub) {
            short8v bf[5];
            #pragma unroll
            for (int g = 0; g < 5; ++g) bf[g] = WTfv[boff[g] + (s * 2 + sub) * 64];
            #pragma unroll
            for (int rt = 0; rt < 4; ++rt) {
                const short8v af = *(const short8v*)&Ab[s & 1][(sub * 4 + rt) * 512 + lane * 8];
                #pragma unroll
                for (int g = 0; g < 5; ++g)
                    acc[rt][g] = __builtin_amdgcn_mfma_f32_16x16x32_bf16(
                        af, bf[g], acc[rt][g], 0, 0, 0);
            }
        }
        __syncthreads();
    }

    // ---- Cell math; gates fully in acc (bias hoisted), child c gathered
    // direct (C layout col=lane&15, row=quad*4+reg; 16-lane 32B transactions).
    float hv[4][4], cv[4][4];
    #pragma unroll
    for (int rt = 0; rt < 4; ++rt) {
        #pragma unroll
        for (int reg = 0; reg < 4; ++reg) {
            const int rr = rt * 16 + quad * 4 + reg;
            const int grow = rowBase + rr;
            float cl, cr;
            if (d == 8) {
                const int b = grow >> 8, i = grow & 255;
                const int tokL = tokens[b * NNODES + 511 + 2 * i];
                const int tokR = tokens[b * NNODES + 512 + 2 * i];
                cl = bf2f(Cleaf[(size_t)tokL * HDIM + j]);
                cr = bf2f(Cleaf[(size_t)tokR * HDIM + j]);
            } else {
                cl = bf2f(csrc[(size_t)(2 * grow) * HDIM + j]);
                cr = bf2f(csrc[(size_t)(2 * grow + 1) * HDIM + j]);
            }
            const float gi  = acc[rt][0][reg] + bz[0];
            const float gfl = acc[rt][1][reg] + bz[1];
            const float gfr = acc[rt][2][reg] + bz[2];
            const float go  = acc[rt][3][reg] + bz[3];
            const float gu  = acc[rt][4][reg] + bz[4];
            const float ii = sigm(gi), fl = sigm(gfl), fr = sigm(gfr), oo = sigm(go);
            const float uu = tanh_fast(gu);
            const float c = ii * uu + fl * cl + fr * cr;
            const float h = oo * tanh_fast(c);
            cv[rt][reg] = c; hv[rt][reg] = h;
            if (d == 0) out[(size_t)grow * HDIM + j] = h;  // n==1 -> b=row
        }
    }
    if (d == 0) return;   // root level: nothing reads hdst/cdst afterwards

    // ---- Writeback via swizzled staging; Ab is dead past the last barrier.
    unsigned short* wb = &Ab[0][0];           // 8192 shorts = 16 KB
    const int jchunk = jl >> 3, jpos = jl & 7;
    #pragma unroll
    for (int rt = 0; rt < 4; ++rt) {
        #pragma unroll
        for (int reg = 0; reg < 4; ++reg) {
            const int rr = rt * 16 + quad * 4 + reg;
            const int roff = ((jchunk + 2 * quad) & 7) * 8 + jpos;  // (rr>>2)&3==quad
            wb[rr * 64 + roff]        = f2bf(hv[rt][reg]);
            wb[4096 + rr * 64 + roff] = f2bf(cv[rt][reg]);
        }
    }
    __syncthreads();
    #pragma unroll
    for (int k2 = 0; k2 < 4; ++k2) {
        const int c = tid + k2 * 256;                // 0..1023
        const int arr = c >> 9, rr = (c >> 3) & 63, u = c & 7;
        const int ru = (u + 2 * ((rr >> 2) & 3)) & 7;
        const short8v v = *(const short8v*)(wb + (arr * 4096 + rr * 64 + ru * 8));
        unsigned short* dstp = (arr ? cdst : hdst) +
            (size_t)(rowBase + rr) * HDIM + jbase + u * 8;
        *(short8v*)dstp = v;
    }
}

// ---------------------------------------------------------------------------
extern "C" void kernel_launch(void* const* d_in, const int* in_sizes, int n_in,
                              void* d_out, int out_size, void* d_ws, size_t ws_size,
                              hipStream_t stream)
{
    const int*   tokens = (const int*)d_in[0];
    const float* emb    = (const float*)d_in[1];
    const float* Wx     = (const float*)d_in[2];
    const float* Ul     = (const float*)d_in[3];
    const float* Ur     = (const float*)d_in[4];
    const float* bias   = (const float*)d_in[5];
    float* out = (float*)d_out;

    // Workspace (bf16): EWb 5.24 | embb 1.05 | WTf 1.97 | Hleaf+Cleaf 2.1 |
    // hA,cA 2x8.4 | hB,cB 2x16.8  -> ~61 MB total.
    const size_t EW_ELEMS  = (size_t)VOCAB * NG;
    const size_t EMB_ELEMS = (size_t)VOCAB * HDIM;
    const size_t WTF_ELEMS = (size_t)80 * 24 * 64 * 8;
    const size_t LT_ELEMS  = (size_t)VOCAB * HDIM;        // each of Hleaf, Cleaf
    const size_t SLOT_A    = (size_t)16384 * HDIM;        // d=7,5,3,1 outputs (max 16384 rows)
    const size_t SLOT_B    = (size_t)32768 * HDIM;        // d=8,6,4,2,0 outputs (max 32768 rows)
    const size_t REQUIRED  = (EW_ELEMS + EMB_ELEMS + WTF_ELEMS + 2 * LT_ELEMS
                              + 2 * (SLOT_A + SLOT_B)) * 2;
    if (ws_size < REQUIRED || d_ws == nullptr) return;   // clean fail, not a fault

    char* ws = (char*)d_ws;
    unsigned short* EWb   = (unsigned short*)ws;
    unsigned short* embb  = EWb + EW_ELEMS;
    unsigned short* WTf   = embb + EMB_ELEMS;
    unsigned short* Hleaf = WTf + WTF_ELEMS;
    unsigned short* Cleaf = Hleaf + LT_ELEMS;
    unsigned short* hA    = Cleaf + LT_ELEMS;
    unsigned short* cA    = hA + SLOT_A;
    unsigned short* hB    = cA + SLOT_A;
    unsigned short* cB    = hB + SLOT_B;

    embb_kernel<<<dim3(256), 256, 0, stream>>>(emb, embb);
    prep_wtf<<<dim3(480), 256, 0, stream>>>(Ul, Ur, Wx, WTf);
    ewb_mfma<<<dim3(4, 32), 256, 0, stream>>>(WTf, embb, bias, EWb);   // feeds leaftab only
    leaftab_kernel<<<dim3(2048), 256, 0, stream>>>(EWb, Hleaf, Cleaf);

    // Levels d=8..0 (jt fastest; 64-row tiles -> NRB = 2<<d).
    // d=8 reads children from Hleaf/Cleaf tables; d<8 from the ping-pong slots.
    for (int d = 8; d >= 0; --d) {
        const int NRB = 2 << d;
        const bool evenD = ((d & 1) == 0);
        const unsigned short* hs = evenD ? hA : hB;   // unused at d==8
        const unsigned short* cs = evenD ? cA : cB;
        unsigned short* hd = evenD ? hB : hA;
        unsigned short* cd = evenD ? cB : cA;
        level_kernel<<<dim3(4, NRB), 256, 0, stream>>>(
            WTf, tokens, embb, Hleaf, Cleaf, hs, cs, bias, hd, cd, out, d);
    }
}

// Round 4
// 356.627 us; speedup vs baseline: 1.0608x; 1.0608x over previous
//
#include <hip/hip_runtime.h>
#include <hip/hip_bf16.h>
#include <math.h>

// Problem constants (from reference)
#define B_SZ   128
#define HDIM   256
#define NG     1280     // 5*H
#define NNODES 1023
#define VOCAB  2048

typedef unsigned int uint32;
typedef short  short8v  __attribute__((ext_vector_type(8)));   // 8 x bf16 (4 VGPR)
typedef float  float4v  __attribute__((ext_vector_type(4)));   // MFMA C/D frag

__device__ __forceinline__ float sigm(float x) {
    return 1.0f / (1.0f + __expf(-x));
}
__device__ __forceinline__ float tanh_fast(float x) {
    return 2.0f / (1.0f + __expf(-2.0f * x)) - 1.0f;
}
__device__ __forceinline__ float bf2f(unsigned short u) {
    return __uint_as_float(((uint32)u) << 16);
}
__device__ __forceinline__ unsigned short f2bf(float f) {
    uint32 x = __float_as_uint(f);
    uint32 r = (x + 0x7FFFu + ((x >> 16) & 1u)) >> 16;   // RNE
    return (unsigned short)r;
}

// Async 16B/lane global->LDS DMA. LDS dest = wave-uniform base + lane*16.
__device__ __forceinline__ void dma16(const unsigned short* gptr, unsigned short* lptr) {
    __builtin_amdgcn_global_load_lds(
        (const __attribute__((address_space(1))) void*)gptr,
        (__attribute__((address_space(3))) void*)lptr, 16, 0, 0);
}

// ---------------------------------------------------------------------------
// embb = bf16(emb) : 2048 x 256.  A-operand for the EW builder + levels' x.
// ---------------------------------------------------------------------------
__global__ __launch_bounds__(256) void embb_kernel(
    const float* __restrict__ emb, unsigned short* __restrict__ embb)
{
    const int t = blockIdx.x * 256 + threadIdx.x;
    const float4 v0 = *(const float4*)(emb + (size_t)t * 8);
    const float4 v1 = *(const float4*)(emb + (size_t)t * 8 + 4);
    short8v o;
    o[0] = (short)f2bf(v0.x); o[1] = (short)f2bf(v0.y);
    o[2] = (short)f2bf(v0.z); o[3] = (short)f2bf(v0.w);
    o[4] = (short)f2bf(v1.x); o[5] = (short)f2bf(v1.y);
    o[6] = (short)f2bf(v1.z); o[7] = (short)f2bf(v1.w);
    *(short8v*)(embb + (size_t)t * 8) = o;
}

// ---------------------------------------------------------------------------
// WTf: fragment-ready bf16 repack of [Ul;Ur;Wx] (K=768, N=1280) for MFMA B.
// short8 index = (ng*24 + ks)*64 + lane ; lane = q*16 + c
//   holds B[k = ks*32 + q*8 + j][col = ng*16 + c],  j = 0..7
// Levels use ALL 24 ks slots (K=768: [hl|hr|x] @ [Ul;Ur;Wx]);
// the EW builder uses ks 16..23 (Wx) only.
// ---------------------------------------------------------------------------
__global__ __launch_bounds__(256) void prep_wtf(
    const float* __restrict__ Ul, const float* __restrict__ Ur,
    const float* __restrict__ Wx, unsigned short* __restrict__ WTf)
{
    const int t = blockIdx.x * 256 + threadIdx.x;   // 0..122879
    const int l = t & 63;
    const int q = l >> 4, c = l & 15;
    const int ks = (t >> 6) % 24;
    const int ng = t / (24 * 64);                    // 0..79
    const int col = ng * 16 + c;
    const int k = ks * 32 + q * 8;
    const float* src = (k < 256) ? (Ul + (size_t)k * NG + col)
                     : (k < 512) ? (Ur + (size_t)(k - 256) * NG + col)
                                 : (Wx + (size_t)(k - 512) * NG + col);
    short8v v;
    #pragma unroll
    for (int j = 0; j < 8; ++j) v[j] = (short)f2bf(src[(size_t)j * NG]);
    *(short8v*)(WTf + (size_t)t * 8) = v;
}

// ---------------------------------------------------------------------------
// EWb = bf16(embb @ Wx + b) via MFMA.  Only consumed by leaftab.
// ---------------------------------------------------------------------------
__global__ __launch_bounds__(256, 2) void ewb_mfma(
    const unsigned short* __restrict__ WTf, const unsigned short* __restrict__ embb,
    const float* __restrict__ bias, unsigned short* __restrict__ EWb)
{
    __shared__ __align__(16) unsigned short Ab[2][4096];   // 16 KB A dbuf
    __shared__ __align__(16) unsigned short wbE[20480];    // 40 KB: 5 gates x 64 rows x 64 cols

    const int tid  = threadIdx.x;
    const int lane = tid & 63;
    const int w    = tid >> 6;                  // 0..3 = col-tile
    const int quad = lane >> 4, col15 = lane & 15;
    const int jt = blockIdx.x;
    const int rowBase = blockIdx.y * 64;        // emb row
    const int jbase   = jt * 64;

    const unsigned short* agp[2];
    unsigned short* ldst[2];
    #pragma unroll
    for (int t = 0; t < 2; ++t) {
        const int ch = 2 * w + t, sub = ch >> 2, rt = ch & 3;
        const int srow = rowBase + rt * 16 + col15;
        agp[t]  = embb + (size_t)srow * HDIM + sub * 32 + quad * 8;
        ldst[t] = &Ab[0][0] + ch * 512;
    }

    const short8v* WTfv = (const short8v*)WTf;
    uint32 boff[5];
    #pragma unroll
    for (int g = 0; g < 5; ++g)
        boff[g] = ((g * 16 + jt * 4 + w) * 24 + 16) * 64 + lane;   // Wx section

    float4v acc[4][5];
    #pragma unroll
    for (int rt = 0; rt < 4; ++rt)
        #pragma unroll
        for (int g = 0; g < 5; ++g)
            #pragma unroll
            for (int e = 0; e < 4; ++e) acc[rt][g][e] = 0.0f;

    dma16(agp[0], ldst[0]); dma16(agp[1], ldst[1]);
    __syncthreads();

    #pragma unroll
    for (int s = 0; s < 4; ++s) {
        if (s < 3) {
            dma16(agp[0] + (s + 1) * 64, ldst[0] + ((s + 1) & 1) * 4096);
            dma16(agp[1] + (s + 1) * 64, ldst[1] + ((s + 1) & 1) * 4096);
        }
        #pragma unroll
        for (int sub = 0; sub < 2; ++sub) {
            short8v bf[5];
            #pragma unroll
            for (int g = 0; g < 5; ++g) bf[g] = WTfv[boff[g] + (s * 2 + sub) * 64];
            #pragma unroll
            for (int rt = 0; rt < 4; ++rt) {
                const short8v af = *(const short8v*)&Ab[s & 1][(sub * 4 + rt) * 512 + lane * 8];
                #pragma unroll
                for (int g = 0; g < 5; ++g)
                    acc[rt][g] = __builtin_amdgcn_mfma_f32_16x16x32_bf16(
                        af, bf[g], acc[rt][g], 0, 0, 0);
            }
        }
        __syncthreads();
    }

    const int jl = w * 16 + col15;
    const int j  = jbase + jl;
    float bz[5];
    #pragma unroll
    for (int g = 0; g < 5; ++g) bz[g] = bias[g * 256 + j];
    const int jchunk = jl >> 3, jpos = jl & 7;

    #pragma unroll
    for (int rt = 0; rt < 4; ++rt) {
        #pragma unroll
        for (int reg = 0; reg < 4; ++reg) {
            const int rr = rt * 16 + quad * 4 + reg;
            const int roff = ((jchunk + 2 * quad) & 7) * 8 + jpos;  // (rr>>2)&3==quad
            #pragma unroll
            for (int g = 0; g < 5; ++g)
                wbE[(g * 64 + rr) * 64 + roff] = f2bf(acc[rt][g][reg] + bz[g]);
        }
    }
    __syncthreads();

    #pragma unroll
    for (int k2 = 0; k2 < 10; ++k2) {
        const int c = tid + k2 * 256;                // 0..2559
        const int g = c >> 9, rr = (c >> 3) & 63, u = c & 7;
        const int ru = (u + 2 * ((rr >> 2) & 3)) & 7;
        const short8v v = *(const short8v*)&wbE[(g * 64 + rr) * 64 + ru * 8];
        *(short8v*)(EWb + (size_t)(rowBase + rr) * NG + g * 256 + jbase + u * 8) = v;
    }
}

// ---------------------------------------------------------------------------
// Leaf-as-table: leaf h/c depend ONLY on the token.
// ---------------------------------------------------------------------------
__global__ __launch_bounds__(256) void leaftab_kernel(
    const unsigned short* __restrict__ EWb,
    unsigned short* __restrict__ Hleaf, unsigned short* __restrict__ Cleaf)
{
    const int t = blockIdx.x * 256 + threadIdx.x;   // 0..524287
    const int tok = t >> 8, j = t & 255;
    const float gi = bf2f(EWb[(size_t)tok * NG + j]);
    const float go = bf2f(EWb[(size_t)tok * NG + 768 + j]);
    const float gu = bf2f(EWb[(size_t)tok * NG + 1024 + j]);
    const float c = sigm(gi) * tanh_fast(gu);
    const float h = sigm(go) * tanh_fast(c);
    Hleaf[t] = f2bf(h);
    Cleaf[t] = f2bf(c);
}

// ---------------------------------------------------------------------------
// Inner level d: MFMA GEMM [hl|hr|x](Mx768) @ [Ul;Ur;Wx](768x1280) + bias
// + LSTM cell.
// R19 change: R3 showed level time ~linear in K-step count -> the 2-barrier
// loop's per-step vmcnt(0) drain is the binding cost, paid 12x.  Now BK=128:
// 6 steps, 80 MFMA/wave/step (~400cy) hides the prefetch, Ab dbuf 32 KB.
// Register discipline (R1 lesson: 164 total = exactly the 3-waves/SIMD edge):
//  - template<LEAF> split so d=8 token-gather math doesn't tax d<8 (and
//    vice versa);
//  - A-gather addresses held as uint32 byte offsets vs SGPR bases
//    (saddr+voffset), not VGPR pointer pairs.
// ---------------------------------------------------------------------------
template <bool LEAF>
__global__ __launch_bounds__(256, 2) void level_kernel(
    const unsigned short* __restrict__ WTf, const int* __restrict__ tokens,
    const unsigned short* __restrict__ embb,
    const unsigned short* __restrict__ Hleaf, const unsigned short* __restrict__ Cleaf,
    const unsigned short* __restrict__ hsrc, const unsigned short* __restrict__ csrc,
    const float* __restrict__ bias,
    unsigned short* __restrict__ hdst, unsigned short* __restrict__ cdst,
    float* __restrict__ out, const int d)
{
    const int n = 1 << d;

    __shared__ __align__(16) unsigned short Ab[2][8192];   // 32 KB: dbuf of 64r x 128k

    const int tid  = threadIdx.x;
    const int lane = tid & 63;
    const int w    = tid >> 6;                  // 0..3 = col-tile AND k-sub
    const int quad = lane >> 4, col15 = lane & 15;
    const int jt = blockIdx.x;                  // 0..3 (fastest)
    const int rowBase = blockIdx.y * 64;
    const int jbase   = jt * 64;

    // ---- A staging: 16 chunks/step (ci = sub*4 + rt); wave w stages sub=w,
    // rt=t for t=0..3.  Chunk = 16 rows x 32 k of bf16 = 1 KB = one dma16.
    // k<256: left-child h | 256..511: right-child h | 512..767: x=embb[tok].
    // Addresses as uint32 byte offsets vs SGPR bases (register thrift).
    const uint32 inrow = (uint32)(w * 64 + quad * 16);   // byte off within 512B row
    uint32 oL[4], oR[4], oN[4];
    #pragma unroll
    for (int t = 0; t < 4; ++t) {
        const int srow = rowBase + t * 16 + col15;
        const int b = srow >> d, i = srow & (n - 1);
        oN[t] = (uint32)tokens[b * NNODES + (n - 1) + i] * 512u + inrow;
        if (LEAF) {
            oL[t] = (uint32)tokens[b * NNODES + 511 + 2 * i] * 512u + inrow;
            oR[t] = (uint32)tokens[b * NNODES + 512 + 2 * i] * 512u + inrow;
        } else {
            oL[t] = (uint32)(2 * srow) * 512u + inrow;
            oR[t] = oL[t] + 512u;
        }
    }
    const char* hb = LEAF ? (const char*)Hleaf : (const char*)hsrc;
    const char* xb = (const char*)embb;

    const short8v* WTfv = (const short8v*)WTf;
    uint32 boff[5];
    #pragma unroll
    for (int g = 0; g < 5; ++g)
        boff[g] = ((g * 16 + jt * 4 + w) * 24) * 64 + lane;   // full K=768 (24 ks)

    // Hoisted bias (uniform per column; L2-hot after first block).
    const int jl = w * 16 + col15;
    const int j  = jbase + jl;
    float bz[5];
    #pragma unroll
    for (int g = 0; g < 5; ++g) bz[g] = bias[g * 256 + j];

    float4v acc[4][5];
    #pragma unroll
    for (int rt = 0; rt < 4; ++rt)
        #pragma unroll
        for (int g = 0; g < 5; ++g)
            #pragma unroll
            for (int e = 0; e < 4; ++e) acc[rt][g][e] = 0.0f;

    // Prologue: stage step 0 (k 0..127 of left-child h) into Ab[0].
    {
        unsigned short* dst = &Ab[0][0] + w * 2048;
        #pragma unroll
        for (int t = 0; t < 4; ++t)
            dma16((const unsigned short*)(hb + oL[t]), dst + t * 512);
    }
    __syncthreads();

    #pragma unroll
    for (int s = 0; s < 6; ++s) {
        if (s < 5) {
            const int sn = s + 1;
            unsigned short* dst = &Ab[sn & 1][0] + w * 2048;
            #pragma unroll
            for (int t = 0; t < 4; ++t) {
                const char* p = (sn < 2) ? (hb + oL[t] + sn * 256)
                              : (sn < 4) ? (hb + oR[t] + (sn - 2) * 256)
                                         : (xb + oN[t] + (sn - 4) * 256);
                dma16((const unsigned short*)p, dst + t * 512);
            }
        }

        #pragma unroll
        for (int sub = 0; sub < 4; ++sub) {
            short8v bf[5];
            #pragma unroll
            for (int g = 0; g < 5; ++g) bf[g] = WTfv[boff[g] + (s * 4 + sub) * 64];
            #pragma unroll
            for (int rt = 0; rt < 4; ++rt) {
                const short8v af = *(const short8v*)&Ab[s & 1][(sub * 4 + rt) * 512 + lane * 8];
                #pragma unroll
                for (int g = 0; g < 5; ++g)
                    acc[rt][g] = __builtin_amdgcn_mfma_f32_16x16x32_bf16(
                        af, bf[g], acc[rt][g], 0, 0, 0);
            }
        }
        __syncthreads();
    }

    // ---- Cell math; gates fully in acc (bias hoisted), child c gathered
    // direct (C layout col=lane&15, row=quad*4+reg; 16-lane 32B transactions).
    float hv[4][4], cv[4][4];
    #pragma unroll
    for (int rt = 0; rt < 4; ++rt) {
        #pragma unroll
        for (int reg = 0; reg < 4; ++reg) {
            const int rr = rt * 16 + quad * 4 + reg;
            const int grow = rowBase + rr;
            float cl, cr;
            if (LEAF) {
                const int b = grow >> 8, i = grow & 255;
                const int tokL = tokens[b * NNODES + 511 + 2 * i];
                const int tokR = tokens[b * NNODES + 512 + 2 * i];
                cl = bf2f(Cleaf[(size_t)tokL * HDIM + j]);
                cr = bf2f(Cleaf[(size_t)tokR * HDIM + j]);
            } else {
                cl = bf2f(csrc[(size_t)(2 * grow) * HDIM + j]);
                cr = bf2f(csrc[(size_t)(2 * grow + 1) * HDIM + j]);
            }
            const float gi  = acc[rt][0][reg] + bz[0];
            const float gfl = acc[rt][1][reg] + bz[1];
            const float gfr = acc[rt][2][reg] + bz[2];
            const float go  = acc[rt][3][reg] + bz[3];
            const float gu  = acc[rt][4][reg] + bz[4];
            const float ii = sigm(gi), fl = sigm(gfl), fr = sigm(gfr), oo = sigm(go);
            const float uu = tanh_fast(gu);
            const float c = ii * uu + fl * cl + fr * cr;
            const float h = oo * tanh_fast(c);
            cv[rt][reg] = c; hv[rt][reg] = h;
            if (!LEAF && d == 0) out[(size_t)grow * HDIM + j] = h;  // n==1 -> b=row
        }
    }
    if (!LEAF && d == 0) return;   // root level: nothing reads hdst/cdst

    // ---- Writeback via swizzled staging; Ab is dead past the last barrier.
    unsigned short* wb = &Ab[0][0];           // 8192 shorts = 16 KB
    const int jchunk = jl >> 3, jpos = jl & 7;
    #pragma unroll
    for (int rt = 0; rt < 4; ++rt) {
        #pragma unroll
        for (int reg = 0; reg < 4; ++reg) {
            const int rr = rt * 16 + quad * 4 + reg;
            const int roff = ((jchunk + 2 * quad) & 7) * 8 + jpos;  // (rr>>2)&3==quad
            wb[rr * 64 + roff]        = f2bf(hv[rt][reg]);
            wb[4096 + rr * 64 + roff] = f2bf(cv[rt][reg]);
        }
    }
    __syncthreads();
    #pragma unroll
    for (int k2 = 0; k2 < 4; ++k2) {
        const int c = tid + k2 * 256;                // 0..1023
        const int arr = c >> 9, rr = (c >> 3) & 63, u = c & 7;
        const int ru = (u + 2 * ((rr >> 2) & 3)) & 7;
        const short8v v = *(const short8v*)(wb + (arr * 4096 + rr * 64 + ru * 8));
        unsigned short* dstp = (arr ? cdst : hdst) +
            (size_t)(rowBase + rr) * HDIM + jbase + u * 8;
        *(short8v*)dstp = v;
    }
}

// ---------------------------------------------------------------------------
extern "C" void kernel_launch(void* const* d_in, const int* in_sizes, int n_in,
                              void* d_out, int out_size, void* d_ws, size_t ws_size,
                              hipStream_t stream)
{
    const int*   tokens = (const int*)d_in[0];
    const float* emb    = (const float*)d_in[1];
    const float* Wx     = (const float*)d_in[2];
    const float* Ul     = (const float*)d_in[3];
    const float* Ur     = (const float*)d_in[4];
    const float* bias   = (const float*)d_in[5];
    float* out = (float*)d_out;

    // Workspace (bf16): EWb 5.24 | embb 1.05 | WTf 1.97 | Hleaf+Cleaf 2.1 |
    // hA,cA 2x8.4 | hB,cB 2x16.8  -> ~61 MB total.
    const size_t EW_ELEMS  = (size_t)VOCAB * NG;
    const size_t EMB_ELEMS = (size_t)VOCAB * HDIM;
    const size_t WTF_ELEMS = (size_t)80 * 24 * 64 * 8;
    const size_t LT_ELEMS  = (size_t)VOCAB * HDIM;        // each of Hleaf, Cleaf
    const size_t SLOT_A    = (size_t)16384 * HDIM;        // d=7,5,3,1 outputs
    const size_t SLOT_B    = (size_t)32768 * HDIM;        // d=8,6,4,2,0 outputs
    const size_t REQUIRED  = (EW_ELEMS + EMB_ELEMS + WTF_ELEMS + 2 * LT_ELEMS
                              + 2 * (SLOT_A + SLOT_B)) * 2;
    if (ws_size < REQUIRED || d_ws == nullptr) return;   // clean fail, not a fault

    char* ws = (char*)d_ws;
    unsigned short* EWb   = (unsigned short*)ws;
    unsigned short* embb  = EWb + EW_ELEMS;
    unsigned short* WTf   = embb + EMB_ELEMS;
    unsigned short* Hleaf = WTf + WTF_ELEMS;
    unsigned short* Cleaf = Hleaf + LT_ELEMS;
    unsigned short* hA    = Cleaf + LT_ELEMS;
    unsigned short* cA    = hA + SLOT_A;
    unsigned short* hB    = cA + SLOT_A;
    unsigned short* cB    = hB + SLOT_B;

    embb_kernel<<<dim3(256), 256, 0, stream>>>(emb, embb);
    prep_wtf<<<dim3(480), 256, 0, stream>>>(Ul, Ur, Wx, WTf);
    ewb_mfma<<<dim3(4, 32), 256, 0, stream>>>(WTf, embb, bias, EWb);   // feeds leaftab only
    leaftab_kernel<<<dim3(2048), 256, 0, stream>>>(EWb, Hleaf, Cleaf);

    // Levels d=8..0 (jt fastest; 64-row tiles -> NRB = 2<<d).
    // d=8 reads children from Hleaf/Cleaf tables; d<8 from the ping-pong slots.
    for (int d = 8; d >= 0; --d) {
        const int NRB = 2 << d;
        const bool evenD = ((d & 1) == 0);
        const unsigned short* hs = evenD ? hA : hB;   // unused at d==8
        const unsigned short* cs = evenD ? cA : cB;
        unsigned short* hd = evenD ? hB : hA;
        unsigned short* cd = evenD ? cB : cA;
        if (d == 8) {
            level_kernel<true><<<dim3(4, NRB), 256, 0, stream>>>(
                WTf, tokens, embb, Hleaf, Cleaf, hs, cs, bias, hd, cd, out, d);
        } else {
            level_kernel<false><<<dim3(4, NRB), 256, 0, stream>>>(
                WTf, tokens, embb, Hleaf, Cleaf, hs, cs, bias, hd, cd, out, d);
        }
    }
}